// Round 9
// baseline (94.993 us; speedup 1.0000x reference)
//
#include <hip/hip_runtime.h>
#include <math.h>

// Problem constants (fixed by setup_inputs): C=64 channels, HW=128*128, bins=256.
#define C_CH 64
#define HW   16384
#define BINS 256

__device__ inline float4 ld4(const float* p) { return *(const float4*)p; }

__device__ inline int lbound(const float* a, float rank) {
    int lo = 0, hi = BINS;
    while (lo < hi) { int mid = (lo + hi) >> 1; if (a[mid] < rank) lo = mid + 1; else hi = mid; }
    return (lo > 255) ? 255 : lo;   // cannot trigger (a[255]=N>=rank); defensive
}

// Single kernel, 64 fully-independent blocks (one channel each) x 1024 threads
// (16 contiguous elems/thread). No cross-block ordering except the final
// non-blocking publish/collect (R8 lesson: pub/sub spin cost +9us on 8 XCDs;
// redundant parallel work is cheaper than any cross-block wait).
//   load:   mask, match_c, match_0, input_c (kept in regs), input_0 (streamed)
//   reduce: ONE shuffle+LDS round for all 9 scalars (3 min/max pairs, msum,
//           2 zero-counts) -> 7 barriers total vs R7's 12
//   hist:   both hist_c and hist_0 per block, branch-free (c==0: identical)
//   scan:   wave 0 -> scdf, wave 1 -> cdf0, in parallel
//   T LUT, marching-pointer CDF-inversion loss from registers
//   finale: byte-identical to R7's proven publish/collect.
__global__ __launch_bounds__(1024, 4) void fused(const float* __restrict__ input,
                                                 const float* __restrict__ match,
                                                 const float* __restrict__ mask,
                                                 unsigned long long* __restrict__ pub,
                                                 float* __restrict__ out) {
    const int c = blockIdx.x, tid = threadIdx.x;
    const int wave = tid >> 6, lane = tid & 63;

    __shared__ float wred[16][12];        // 9 used, padded
    __shared__ int   hist_c[BINS], hist_0[BINS];
    __shared__ float scdf[BINS], cdf0[BINS], sT[BINS];
    __shared__ float facc[16];

    // ---------------- load phase: all 5 streams up front ----------------
    float mval[16], mval0[16], xval[16];
    float mn_c = INFINITY, mx_c = -INFINITY;
    float mn_0 = INFINITY, mx_0 = -INFINITY;
    float xmn  = INFINITY, xmx  = -INFINITY;
    float msum = 0.0f;
    int zc_c = 0, zc_0 = 0;
    {
        const float* mkp = mask  + 16 * tid;
        const float* mcp = match + c * HW + 16 * tid;
        const float* m0p = match + 16 * tid;            // ch0 match (L2/L3-hot)
        const float* xcp = input + c * HW + 16 * tid;
        const float* x0p = input + 16 * tid;            // ch0 input (L2/L3-hot)
        #pragma unroll
        for (int k = 0; k < 4; k++) {
            float4 kq = ld4(mkp + 4 * k);
            float4 mc = ld4(mcp + 4 * k);
            float4 m0 = ld4(m0p + 4 * k);
            float4 xc = ld4(xcp + 4 * k);
            float4 x0 = ld4(x0p + 4 * k);
            float kk[4] = { kq.x, kq.y, kq.z, kq.w };
            float ac[4] = { mc.x, mc.y, mc.z, mc.w };
            float a0[4] = { m0.x, m0.y, m0.z, m0.w };
            float bc[4] = { xc.x, xc.y, xc.z, xc.w };
            float b0[4] = { x0.x, x0.y, x0.z, x0.w };
            #pragma unroll
            for (int j = 0; j < 4; j++) {
                int i = 4 * k + j;
                msum += kk[j];                               // 0/1 values: exact
                float vc = ac[j] * kk[j];
                float v0 = a0[j] * kk[j];
                float xc2 = bc[j] * kk[j];
                float x02 = b0[j] * kk[j];
                mval[i] = vc;  mval0[i] = v0;  xval[i] = xc2;
                mn_c = fminf(mn_c, vc);  mx_c = fmaxf(mx_c, vc);
                mn_0 = fminf(mn_0, v0);  mx_0 = fmaxf(mx_0, v0);
                xmn  = fminf(xmn, x02);  xmx  = fmaxf(xmx, x02);
                zc_c += (vc == 0.0f) ? 1 : 0;               // zero-count: bin-width-free
                zc_0 += (v0 == 0.0f) ? 1 : 0;
            }
        }
    }

    // ---------------- ONE unified reduction round ----------------
    float fzc = (float)zc_c, fz0 = (float)zc_0;             // counts <= 16384: exact
    #pragma unroll
    for (int s = 32; s > 0; s >>= 1) {
        mn_c = fminf(mn_c, __shfl_xor(mn_c, s, 64));
        mx_c = fmaxf(mx_c, __shfl_xor(mx_c, s, 64));
        mn_0 = fminf(mn_0, __shfl_xor(mn_0, s, 64));
        mx_0 = fmaxf(mx_0, __shfl_xor(mx_0, s, 64));
        xmn  = fminf(xmn,  __shfl_xor(xmn,  s, 64));
        xmx  = fmaxf(xmx,  __shfl_xor(xmx,  s, 64));
        msum += __shfl_xor(msum, s, 64);
        fzc  += __shfl_xor(fzc,  s, 64);
        fz0  += __shfl_xor(fz0,  s, 64);
    }
    if (lane == 0) {
        wred[wave][0] = mn_c; wred[wave][1] = mx_c;
        wred[wave][2] = mn_0; wred[wave][3] = mx_0;
        wred[wave][4] = xmn;  wred[wave][5] = xmx;
        wred[wave][6] = msum; wred[wave][7] = fzc; wred[wave][8] = fz0;
    }
    if (tid < BINS) { hist_c[tid] = 0; hist_0[tid] = 0; }
    __syncthreads();                                        // B1
    mn_c = wred[0][0]; mx_c = wred[0][1];
    mn_0 = wred[0][2]; mx_0 = wred[0][3];
    xmn  = wred[0][4]; xmx  = wred[0][5];
    msum = wred[0][6]; fzc  = wred[0][7]; fz0 = wred[0][8];
    #pragma unroll
    for (int r = 1; r < 16; r++) {
        mn_c = fminf(mn_c, wred[r][0]); mx_c = fmaxf(mx_c, wred[r][1]);
        mn_0 = fminf(mn_0, wred[r][2]); mx_0 = fmaxf(mx_0, wred[r][3]);
        xmn  = fminf(xmn,  wred[r][4]); xmx  = fmaxf(xmx,  wred[r][5]);
        msum += wred[r][6]; fzc += wred[r][7]; fz0 += wred[r][8];
    }

    // torch.histc: w=(mx-mn)/bins; safe_w = w>0 ? w : 1  (/256 exact)
    float wc_ = (mx_c - mn_c) * (1.0f / 256.0f);
    float swc = (wc_ > 0.0f) ? wc_ : 1.0f;
    float w0_ = (mx_0 - mn_0) * (1.0f / 256.0f);
    float sw0 = (w0_ > 0.0f) ? w0_ : 1.0f;

    // ---------------- both histograms, branch-free ----------------
    #pragma unroll
    for (int j = 0; j < 16; j++) {
        if (mval[j] != 0.0f) {                              // zeros pre-counted
            float bb = floorf((mval[j] - mn_c) / swc);
            bb = fminf(fmaxf(bb, 0.0f), 255.0f);            // clip in float like the ref
            atomicAdd(&hist_c[(int)bb], 1);
        }
        if (mval0[j] != 0.0f) {
            float bb = floorf((mval0[j] - mn_0) / sw0);
            bb = fminf(fmaxf(bb, 0.0f), 255.0f);
            atomicAdd(&hist_0[(int)bb], 1);
        }
    }
    __syncthreads();                                        // B2
    if (tid == 0) {                                         // zero-bins (same calc as per-elem)
        float bb = fminf(fmaxf(floorf((0.0f - mn_c) / swc), 0.0f), 255.0f);
        hist_c[(int)bb] += (int)fzc;
        float b0 = fminf(fmaxf(floorf((0.0f - mn_0) / sw0), 0.0f), 255.0f);
        hist_0[(int)b0] += (int)fz0;
    }
    __syncthreads();                                        // B3

    // ---------------- parallel scans: wave0 -> scdf, wave1 -> cdf0 ----------------
    if (wave < 2) {
        const int* src = (wave == 0) ? hist_c : hist_0;
        float* dst = (wave == 0) ? scdf : cdf0;
        int h0 = src[4 * lane], h1 = src[4 * lane + 1];
        int h2 = src[4 * lane + 2], h3 = src[4 * lane + 3];
        int p1 = h0 + h1, p2 = p1 + h2, s4 = p2 + h3;
        int sc = s4;
        #pragma unroll
        for (int off = 1; off < 64; off <<= 1) {
            int t = __shfl_up(sc, off, 64);
            if (lane >= off) sc += t;
        }
        int e = sc - s4;
        dst[4 * lane] = (float)(e + h0);      dst[4 * lane + 1] = (float)(e + p1);
        dst[4 * lane + 2] = (float)(e + p2);  dst[4 * lane + 3] = (float)(e + s4);
    }
    __syncthreads();                                        // B4

    // ---------------- T LUT from cdf0 + ch0-input stats ----------------
    if (tid < BINS) {
        float step = (xmx - xmn) * (1.0f / 256.0f);
        float rank = (float)(tid + 1);
        int idx = lbound(cdf0, rank);
        float cp = (idx > 0) ? cdf0[idx - 1] : 0.0f;
        float cc = cdf0[idx];
        float ratio = fminf(fmaxf((rank - cp) / (1e-8f + cc), 0.0f), 1.0f);
        sT[tid] = xmn + (ratio + (float)idx) * step;
    }
    __syncthreads();                                        // B5

    // ---------------- loss over channel c (pure registers) ----------------
    float acc = 0.0f;
    {
        int lo = lbound(scdf, (float)(16 * tid + 1));       // one search, then march
        #pragma unroll
        for (int j = 0; j < 16; j++) {
            float rnk = (float)(16 * tid + j + 1);
            while (scdf[lo] < rnk) lo++;                    // scdf[255]=N bounds it
            float d = sT[lo] - xval[j];
            acc += d * d;
        }
        #pragma unroll
        for (int s = 32; s > 0; s >>= 1) acc += __shfl_xor(acc, s, 64);
        if (lane == 0) facc[wave] = acc;
        __syncthreads();                                    // B6
    }

    // ---------------- non-blocking finale (byte-identical to R7) ----------------
    if (tid == 0) {
        float tot = 0.0f;
        #pragma unroll
        for (int j = 0; j < 16; j++) tot += facc[j];
        unsigned long long pk = (1ULL << 32) | (unsigned long long)__float_as_uint(tot);
        atomicExch(&pub[c], pk);
    }
    __syncthreads();                                        // B7: own publish first
    if (wave == 0) {
        unsigned long long vv = atomicAdd(&pub[lane], 0ULL);    // lane <-> block
        bool got = ((vv >> 32) == 1ULL);
        unsigned long long bal = __ballot(got);
        float p = got ? __uint_as_float((unsigned int)vv) : 0.0f;
        #pragma unroll
        for (int s = 32; s > 0; s >>= 1) p += __shfl_xor(p, s, 64);
        if (lane == 0 && bal == ~0ULL) {                    // saw all 64: finalize
            double loss = (double)p * (double)msum /
                          ((double)C_CH * (double)HW * (double)HW);
            out[0] = (float)loss;
        }
    }
}

extern "C" void kernel_launch(void* const* d_in, const int* in_sizes, int n_in,
                              void* d_out, int out_size, void* d_ws, size_t ws_size,
                              hipStream_t stream) {
    const float* input = (const float*)d_in[0];
    const float* match = (const float*)d_in[1];
    const float* mask  = (const float*)d_in[2];
    unsigned long long* pub = (unsigned long long*)d_ws;    // 64 cells
    float* out = (float*)d_out;

    fused<<<C_CH, 1024, 0, stream>>>(input, match, mask, pub, out);
}